// Round 6
// baseline (243.199 us; speedup 1.0000x reference)
//
#include <hip/hip_runtime.h>
#include <stdint.h>

typedef unsigned short u16;
typedef __attribute__((ext_vector_type(8))) short short8;
typedef __attribute__((ext_vector_type(4))) float f32x4;
typedef __attribute__((ext_vector_type(8))) u16 u16x8;

// 2*SCALE/SOFT_CAP*log2(e) = 2*0.125/50*log2(e)
#define CEXP2 0.0072134752044448f
#define C2L 144.26950408889634f   // 100*log2(e)

static __device__ __forceinline__ u16 f2bf(float f) {
  union { float f; unsigned u; } v; v.f = f;
  unsigned r = v.u + 0x7fffu + ((v.u >> 16) & 1u);
  return (u16)(r >> 16);
}

static __device__ __forceinline__ void gload16(const void* g, void* l) {
  __builtin_amdgcn_global_load_lds(
      (const __attribute__((address_space(1))) void*)g,
      (__attribute__((address_space(3))) void*)l, 16, 0, 0);
}

// ---------------- cast x fp32 -> bf16 ----------------
__global__ void __launch_bounds__(256) cast_x_kernel(const float* __restrict__ x,
                                                     u16* __restrict__ xb, int n) {
  int i = (blockIdx.x * 256 + threadIdx.x) * 8;
  if (i >= n) return;
  f32x4 a = *(const f32x4*)(x + i);
  f32x4 b = *(const f32x4*)(x + i + 4);
  u16x8 o;
  o[0] = f2bf(a[0]); o[1] = f2bf(a[1]); o[2] = f2bf(a[2]); o[3] = f2bf(a[3]);
  o[4] = f2bf(b[0]); o[5] = f2bf(b[1]); o[6] = f2bf(b[2]); o[7] = f2bf(b[3]);
  *(u16x8*)(xb + i) = o;
}

// ------- all 4 weight transposes in one launch -------
__global__ void __launch_bounds__(256) wtrans_all_kernel(const float* __restrict__ Wq,
                                                         const float* __restrict__ Wk,
                                                         const float* __restrict__ Wv,
                                                         const float* __restrict__ Wo,
                                                         u16* __restrict__ WqkvT,
                                                         u16* __restrict__ WoT) {
  __shared__ u16 tile[64][68];
  int id = blockIdx.x;
  const float* W; u16* WT; int ncols, row_off, cx, ry;
  if (id < 256)      { W = Wq; WT = WqkvT; ncols = 1024; row_off = 0;    cx = id & 15;        ry = id >> 4; }
  else if (id < 320) { W = Wk; WT = WqkvT; ncols = 256;  row_off = 1024; cx = (id - 256) & 3; ry = (id - 256) >> 2; }
  else if (id < 384) { W = Wv; WT = WqkvT; ncols = 256;  row_off = 1280; cx = (id - 320) & 3; ry = (id - 320) >> 2; }
  else               { W = Wo; WT = WoT;   ncols = 1024; row_off = 0;    cx = (id - 384) & 15; ry = (id - 384) >> 4; }
  int c0 = cx * 64, r0 = ry * 64;
  int cc = threadIdx.x & 63, rb = threadIdx.x >> 6;
#pragma unroll
  for (int i = 0; i < 16; i++) {
    int r = rb + i * 4;
    tile[r][cc] = f2bf(W[(size_t)(r0 + r) * ncols + c0 + cc]);
  }
  __syncthreads();
#pragma unroll
  for (int i = 0; i < 16; i++) {
    int n = rb + i * 4;
    WT[(size_t)(row_off + c0 + n) * 1024 + r0 + cc] = tile[cc][n];
  }
}

// ---------------- QKV GEMM with fused QKNorm epilogue ----------------
__global__ void __launch_bounds__(256) gemm_qkv_kernel(const u16* __restrict__ A,
                                                       const u16* __restrict__ Bt,
                                                       const float* __restrict__ qw,
                                                       const float* __restrict__ kw,
                                                       u16* __restrict__ Qn,
                                                       u16* __restrict__ Kn,
                                                       u16* __restrict__ Vc) {
  __shared__ __align__(16) u16 ldsA[128 * 64];
  __shared__ __align__(16) u16 ldsB[128 * 64];
  const int K = 1024;
  int tid = threadIdx.x;
  int l = tid & 63, w = tid >> 6;
  int wm = w >> 1, wn = w & 1;
  int fr = l & 15, fg = l >> 4;
  int m0 = blockIdx.y * 128, n0 = blockIdx.x * 128;
  f32x4 acc[4][4];
#pragma unroll
  for (int i = 0; i < 4; i++)
#pragma unroll
    for (int j = 0; j < 4; j++) acc[i][j] = (f32x4)(0.0f);

  int lrow = l >> 3;
  int lcol = (l & 7) * 8;
  for (int k0 = 0; k0 < K; k0 += 64) {
#pragma unroll
    for (int i = 0; i < 4; i++) {
      int ci = w * 4 + i;
      gload16(A + (size_t)(m0 + ci * 8 + lrow) * K + k0 + lcol, ldsA + ci * 512);
      gload16(Bt + (size_t)(n0 + ci * 8 + lrow) * K + k0 + lcol, ldsB + ci * 512);
    }
    __syncthreads();
#pragma unroll
    for (int ks = 0; ks < 2; ks++) {
      short8 av[4], bv[4];
#pragma unroll
      for (int mb = 0; mb < 4; mb++)
        av[mb] = *(const short8*)(ldsA + (wm * 64 + mb * 16 + fr) * 64 + ks * 32 + fg * 8);
#pragma unroll
      for (int nb = 0; nb < 4; nb++)
        bv[nb] = *(const short8*)(ldsB + (wn * 64 + nb * 16 + fr) * 64 + ks * 32 + fg * 8);
#pragma unroll
      for (int mb = 0; mb < 4; mb++)
#pragma unroll
        for (int nb = 0; nb < 4; nb++)
          acc[mb][nb] = __builtin_amdgcn_mfma_f32_16x16x32_bf16(av[mb], bv[nb], acc[mb][nb], 0, 0, 0);
    }
    __syncthreads();
  }

  int hc = n0 + wn * 64;
  int m_base = m0 + wm * 64;
  if (hc < 1280) {
    const float* wptr = (hc < 1024) ? qw : kw;
    float wv[4];
#pragma unroll
    for (int nb = 0; nb < 4; nb++) wv[nb] = wptr[nb * 16 + fr];
#pragma unroll
    for (int mb = 0; mb < 4; mb++)
#pragma unroll
      for (int r = 0; r < 4; r++) {
        float ss = acc[mb][0][r] * acc[mb][0][r] + acc[mb][1][r] * acc[mb][1][r] +
                   acc[mb][2][r] * acc[mb][2][r] + acc[mb][3][r] * acc[mb][3][r];
        ss += __shfl_xor(ss, 1, 64);
        ss += __shfl_xor(ss, 2, 64);
        ss += __shfl_xor(ss, 4, 64);
        ss += __shfl_xor(ss, 8, 64);
        float rn = rsqrtf(ss * (1.0f / 64.0f) + 1e-6f);
        int row = m_base + mb * 16 + fg * 4 + r;
        int b = row >> 11, t = row & 2047;
        size_t base;
        u16* dst;
        if (hc < 1024) { dst = Qn; base = ((size_t)(b * 16 + (hc >> 6)) * 2048 + t) * 64; }
        else           { dst = Kn; base = ((size_t)(b * 4 + ((hc - 1024) >> 6)) * 2048 + t) * 64; }
#pragma unroll
        for (int nb = 0; nb < 4; nb++)
          dst[base + nb * 16 + fr] = f2bf(acc[mb][nb][r] * rn * wv[nb]);
      }
  } else {
    int kv = (hc - 1280) >> 6;
#pragma unroll
    for (int mb = 0; mb < 4; mb++)
#pragma unroll
      for (int r = 0; r < 4; r++) {
        int row = m_base + mb * 16 + fg * 4 + r;
        int b = row >> 11, t = row & 2047;
        size_t base = ((size_t)(b * 4 + kv) * 2048 + t) * 64;
#pragma unroll
        for (int nb = 0; nb < 4; nb++)
          Vc[base + nb * 16 + fr] = f2bf(acc[mb][nb][r]);
      }
  }
}

// ---------------- plain GEMM (out-proj) ----------------
__global__ void __launch_bounds__(256) gemm_bt_kernel(const u16* __restrict__ A,
                                                      const u16* __restrict__ Bt,
                                                      float* __restrict__ C,
                                                      int M, int N, int K) {
  __shared__ __align__(16) u16 ldsA[128 * 64];
  __shared__ __align__(16) u16 ldsB[128 * 64];
  int tid = threadIdx.x;
  int l = tid & 63, w = tid >> 6;
  int wm = w >> 1, wn = w & 1;
  int fr = l & 15, fg = l >> 4;
  int m0 = blockIdx.y * 128, n0 = blockIdx.x * 128;
  f32x4 acc[4][4];
#pragma unroll
  for (int i = 0; i < 4; i++)
#pragma unroll
    for (int j = 0; j < 4; j++) acc[i][j] = (f32x4)(0.0f);

  int lrow = l >> 3;
  int lcol = (l & 7) * 8;
  for (int k0 = 0; k0 < K; k0 += 64) {
#pragma unroll
    for (int i = 0; i < 4; i++) {
      int ci = w * 4 + i;
      gload16(A + (size_t)(m0 + ci * 8 + lrow) * K + k0 + lcol, ldsA + ci * 512);
      gload16(Bt + (size_t)(n0 + ci * 8 + lrow) * K + k0 + lcol, ldsB + ci * 512);
    }
    __syncthreads();
#pragma unroll
    for (int ks = 0; ks < 2; ks++) {
      short8 av[4], bv[4];
#pragma unroll
      for (int mb = 0; mb < 4; mb++)
        av[mb] = *(const short8*)(ldsA + (wm * 64 + mb * 16 + fr) * 64 + ks * 32 + fg * 8);
#pragma unroll
      for (int nb = 0; nb < 4; nb++)
        bv[nb] = *(const short8*)(ldsB + (wn * 64 + nb * 16 + fr) * 64 + ks * 32 + fg * 8);
#pragma unroll
      for (int mb = 0; mb < 4; mb++)
#pragma unroll
        for (int nb = 0; nb < 4; nb++)
          acc[mb][nb] = __builtin_amdgcn_mfma_f32_16x16x32_bf16(av[mb], bv[nb], acc[mb][nb], 0, 0, 0);
    }
    __syncthreads();
  }
#pragma unroll
  for (int mb = 0; mb < 4; mb++)
#pragma unroll
    for (int nb = 0; nb < 4; nb++)
#pragma unroll
      for (int r = 0; r < 4; r++)
        C[(size_t)(m0 + wm * 64 + mb * 16 + fg * 4 + r) * N + (n0 + wn * 64 + nb * 16 + fr)] =
            acc[mb][nb][r];
}

// ---------------- V transpose bf16 -> Vt[d][t] ----------------
__global__ void __launch_bounds__(256) vtrans_kernel(const u16* __restrict__ Vc,
                                                     u16* __restrict__ Vt) {
  __shared__ u16 tile[64][68];
  int bkv = blockIdx.y;
  int t0 = blockIdx.x * 64;
  int cc = threadIdx.x & 63, rb = threadIdx.x >> 6;
#pragma unroll
  for (int i = 0; i < 16; i++) {
    int tt = rb + i * 4;
    tile[tt][cc] = Vc[(size_t)(bkv * 2048 + t0 + tt) * 64 + cc];
  }
  __syncthreads();
#pragma unroll
  for (int i = 0; i < 16; i++) {
    int d = rb + i * 4;
    Vt[(size_t)(bkv * 64 + d) * 2048 + t0 + cc] = tile[cc][d];
  }
}

// ---------------- Flash attention: 8 waves, QBLK=128, static-max softmax ----------------
// Soft-cap bounds logits to +-50 => +-72.135 in log2 domain. Static max M = 50*log2e:
// p = exp2(sl - M) = exp2(-C2L/(e+1)). Self-key (raw logit >= 0) guarantees
// p_self >= 2^-72.13 so lsum never underflows. No running max, no rescale,
// no per-tile cross-lane ops; lsum reduced once after the loop.
static __device__ __forceinline__ void stage_k(const u16* Kb, u16* dst, int kb0, int tid) {
  int row = tid >> 3, c8 = tid & 7;
  gload16(Kb + (size_t)(kb0 + row) * 64 + ((c8 ^ (row & 7)) << 3), dst + tid * 8);
}

__global__ void __launch_bounds__(512, 4) attn_kernel(const u16* __restrict__ Qn,
                                                      const u16* __restrict__ Kn,
                                                      const u16* __restrict__ Vt,
                                                      u16* __restrict__ AO) {
  __shared__ __align__(16) u16 ldsK[2][4096];   // K dbuf: 64 rows x 64 cols (swizzled)
  __shared__ __align__(16) u16 plds[8][16][72];
  int tid = threadIdx.x;
  int w = tid >> 6, l = tid & 63;
  int fr = l & 15, fg = l >> 4;
  // XCD pinning by (b,kvh); heavy qtiles first (LPT)
  int i = blockIdx.x;
  int g = i & 7, j = i >> 3;
  int hq = j & 3;
  int qtile = 15 - (j >> 2);
  int b = g >> 2, kvh = g & 3, h = kvh * 4 + hq;
  const u16* Qb = Qn + (size_t)((b * 16 + h) * 2048) * 64;
  const u16* Kb = Kn + (size_t)((b * 4 + kvh) * 2048) * 64;
  const u16* Vb = Vt + (size_t)((b * 4 + kvh) * 64) * 2048;
  int qt0 = qtile * 128 + w * 16;

  short8 qf[2];
#pragma unroll
  for (int ks = 0; ks < 2; ks++)
    qf[ks] = *(const short8*)(Qb + (size_t)(qt0 + fr) * 64 + ks * 32 + fg * 8);

  f32x4 of[4];
#pragma unroll
  for (int ii = 0; ii < 4; ii++) of[ii] = (f32x4)(0.0f);
  float lsum = 0.0f;   // lane-local partial: q = qt0+fr, k in {kb*16+fg*4+r}
  u16(*P)[72] = plds[w];

  int nt = 2 * qtile + 2;
  stage_k(Kb, ldsK[0], 0, tid);

  for (int t = 0; t < nt; t++) {
    int kb0 = t * 64;
    // V prefetch (regs): issued at iter top, consumed at PV
    short8 vf[2][4];
#pragma unroll
    for (int ks = 0; ks < 2; ks++)
#pragma unroll
      for (int db = 0; db < 4; db++)
        vf[ks][db] = *(const short8*)(Vb + (size_t)(db * 16 + fr) * 2048 + kb0 + ks * 32 + fg * 8);
    int tn = (t + 1 < nt) ? t + 1 : t;
    stage_k(Kb, ldsK[(t + 1) & 1], tn * 64, tid);
    // outstanding: K(t)x1 + V(t)x8 + K(t+1)x1 = 10 -> vmcnt(9) drains K(t)
    asm volatile("s_waitcnt vmcnt(9)" ::: "memory");
    __builtin_amdgcn_s_barrier();
    asm volatile("" ::: "memory");

    if (kb0 <= qt0 + 15) {  // wave-uniform skip of fully-masked tiles
      const u16* kbuf = ldsK[t & 1];
      // S^T = K Q^T : sf[kb][r] = S[k=kb0+kb*16+fg*4+r][q=qt0+fr]
      f32x4 sf[4];
#pragma unroll
      for (int kb = 0; kb < 4; kb++) sf[kb] = (f32x4)(0.0f);
      __builtin_amdgcn_s_setprio(1);
#pragma unroll
      for (int ks = 0; ks < 2; ks++) {
#pragma unroll
        for (int kb = 0; kb < 4; kb++) {
          short8 kf = *(const short8*)(kbuf + (kb * 16 + fr) * 64 +
                                       ((((ks << 2) + fg) ^ (fr & 7)) << 3));
          sf[kb] = __builtin_amdgcn_mfma_f32_16x16x32_bf16(kf, qf[ks], sf[kb], 0, 0, 0);
        }
      }
      __builtin_amdgcn_s_setprio(0);
      // cap + static-max exp in one shot: p = exp2(-C2L / (exp2(s*CEXP2)+1))
      float rs = 0.0f;
#pragma unroll
      for (int kb = 0; kb < 4; kb++)
#pragma unroll
        for (int r = 0; r < 4; r++) {
          float e = __builtin_amdgcn_exp2f(sf[kb][r] * CEXP2);
          sf[kb][r] = __builtin_amdgcn_exp2f(-C2L * __builtin_amdgcn_rcpf(e + 1.0f));
        }
      if (kb0 + 63 > qt0) {  // diagonal tiles: causal mask (k > q)
#pragma unroll
        for (int kb = 0; kb < 4; kb++)
#pragma unroll
          for (int r = 0; r < 4; r++)
            if (kb0 + kb * 16 + fg * 4 + r > qt0 + fr) sf[kb][r] = 0.0f;
      }
#pragma unroll
      for (int kb = 0; kb < 4; kb++)
#pragma unroll
        for (int r = 0; r < 4; r++) rs += sf[kb][r];
      lsum += rs;
      // pack P -> LDS (wave-private): P[q=fr][k=kb*16+fg*4+2rp]
#pragma unroll
      for (int kb = 0; kb < 4; kb++)
#pragma unroll
        for (int rp = 0; rp < 2; rp++) {
          unsigned pk;
          asm("v_cvt_pk_bf16_f32 %0, %1, %2" : "=v"(pk)
              : "v"(sf[kb][2 * rp]), "v"(sf[kb][2 * rp + 1]));
          *(unsigned*)(&P[fr][kb * 16 + fg * 4 + 2 * rp]) = pk;
        }
      short8 pa[2];
#pragma unroll
      for (int ks = 0; ks < 2; ks++)
        pa[ks] = *(const short8*)(&P[fr][ks * 32 + fg * 8]);
      __builtin_amdgcn_s_setprio(1);
#pragma unroll
      for (int ks = 0; ks < 2; ks++)
#pragma unroll
        for (int db = 0; db < 4; db++)
          of[db] = __builtin_amdgcn_mfma_f32_16x16x32_bf16(pa[ks], vf[ks][db], of[db], 0, 0, 0);
      __builtin_amdgcn_s_setprio(0);
    }
    asm volatile("" ::: "memory");
    __builtin_amdgcn_s_barrier();
  }
  asm volatile("s_waitcnt vmcnt(0)" ::: "memory");  // drain clamped last prefetch
  // single final reduce across fg groups
  lsum += __shfl_xor(lsum, 16, 64);
  lsum += __shfl_xor(lsum, 32, 64);
  float linv = __builtin_amdgcn_rcpf(lsum);
#pragma unroll
  for (int r = 0; r < 4; r++) {
    float li = __shfl(linv, fg * 4 + r, 16);
#pragma unroll
    for (int db = 0; db < 4; db++)
      AO[(size_t)(b * 2048 + qt0 + fg * 4 + r) * 1024 + h * 64 + db * 16 + fr] =
          f2bf(of[db][r] * li);
  }
}

extern "C" void kernel_launch(void* const* d_in, const int* in_sizes, int n_in,
                              void* d_out, int out_size, void* d_ws, size_t ws_size,
                              hipStream_t stream) {
  (void)in_sizes; (void)n_in; (void)out_size; (void)ws_size;
  const float* x  = (const float*)d_in[0];
  const float* Wq = (const float*)d_in[1];
  const float* Wk = (const float*)d_in[2];
  const float* Wv = (const float*)d_in[3];
  const float* Wo = (const float*)d_in[4];
  const float* qw = (const float*)d_in[5];
  const float* kw = (const float*)d_in[6];
  float* out = (float*)d_out;

  char* p = (char*)d_ws;
  u16* xb    = (u16*)p;   p += (size_t)4096 * 1024 * 2;
  u16* WqkvT = (u16*)p;   p += (size_t)1536 * 1024 * 2;
  u16* WoT   = (u16*)p;   p += (size_t)1024 * 1024 * 2;
  u16* Qn    = (u16*)p;   p += (size_t)2 * 16 * 2048 * 64 * 2;
  u16* Kn    = (u16*)p;   p += (size_t)2 * 4 * 2048 * 64 * 2;
  u16* Vc    = (u16*)p;   p += (size_t)2 * 4 * 2048 * 64 * 2;
  u16* Vt    = (u16*)p;   p += (size_t)2 * 4 * 64 * 2048 * 2;
  u16* AO    = (u16*)p;   p += (size_t)4096 * 1024 * 2;

  cast_x_kernel<<<2048, 256, 0, stream>>>(x, xb, 4096 * 1024);
  wtrans_all_kernel<<<640, 256, 0, stream>>>(Wq, Wk, Wv, Wo, WqkvT, WoT);
  gemm_qkv_kernel<<<dim3(12, 32), 256, 0, stream>>>(xb, WqkvT, qw, kw, Qn, Kn, Vc);
  vtrans_kernel<<<dim3(32, 8), 256, 0, stream>>>(Vc, Vt);
  attn_kernel<<<512, 512, 0, stream>>>(Qn, Kn, Vt, AO);
  gemm_bt_kernel<<<dim3(8, 32), 256, 0, stream>>>(AO, WoT, out, 4096, 1024, 1024);
}

// Round 7
// 192.489 us; speedup vs baseline: 1.2634x; 1.2634x over previous
//
#include <hip/hip_runtime.h>
#include <stdint.h>

typedef unsigned short u16;
typedef __attribute__((ext_vector_type(8))) short short8;
typedef __attribute__((ext_vector_type(4))) float f32x4;
typedef __attribute__((ext_vector_type(8))) u16 u16x8;

#define LOG2E 1.4426950408889634f
#define CEXP2 0.0072134752044448f   // 2*SCALE/SOFT_CAP*log2e
#define C1L 72.13475204444817f      // 50*log2(e)
#define C2L 144.26950408889634f     // 100*log2(e)

static __device__ __forceinline__ u16 f2bf(float f) {
  union { float f; unsigned u; } v; v.f = f;
  unsigned r = v.u + 0x7fffu + ((v.u >> 16) & 1u);
  return (u16)(r >> 16);
}

static __device__ __forceinline__ void gload16(const void* g, void* l) {
  __builtin_amdgcn_global_load_lds(
      (const __attribute__((address_space(1))) void*)g,
      (__attribute__((address_space(3))) void*)l, 16, 0, 0);
}

// ---------------- cast x fp32 -> bf16 ----------------
__global__ void __launch_bounds__(256) cast_x_kernel(const float* __restrict__ x,
                                                     u16* __restrict__ xb, int n) {
  int i = (blockIdx.x * 256 + threadIdx.x) * 8;
  if (i >= n) return;
  f32x4 a = *(const f32x4*)(x + i);
  f32x4 b = *(const f32x4*)(x + i + 4);
  u16x8 o;
  o[0] = f2bf(a[0]); o[1] = f2bf(a[1]); o[2] = f2bf(a[2]); o[3] = f2bf(a[3]);
  o[4] = f2bf(b[0]); o[5] = f2bf(b[1]); o[6] = f2bf(b[2]); o[7] = f2bf(b[3]);
  *(u16x8*)(xb + i) = o;
}

// ------- all 4 weight transposes in one launch -------
__global__ void __launch_bounds__(256) wtrans_all_kernel(const float* __restrict__ Wq,
                                                         const float* __restrict__ Wk,
                                                         const float* __restrict__ Wv,
                                                         const float* __restrict__ Wo,
                                                         u16* __restrict__ WqkvT,
                                                         u16* __restrict__ WoT) {
  __shared__ u16 tile[64][68];
  int id = blockIdx.x;
  const float* W; u16* WT; int ncols, row_off, cx, ry;
  if (id < 256)      { W = Wq; WT = WqkvT; ncols = 1024; row_off = 0;    cx = id & 15;        ry = id >> 4; }
  else if (id < 320) { W = Wk; WT = WqkvT; ncols = 256;  row_off = 1024; cx = (id - 256) & 3; ry = (id - 256) >> 2; }
  else if (id < 384) { W = Wv; WT = WqkvT; ncols = 256;  row_off = 1280; cx = (id - 320) & 3; ry = (id - 320) >> 2; }
  else               { W = Wo; WT = WoT;   ncols = 1024; row_off = 0;    cx = (id - 384) & 15; ry = (id - 384) >> 4; }
  int c0 = cx * 64, r0 = ry * 64;
  int cc = threadIdx.x & 63, rb = threadIdx.x >> 6;
#pragma unroll
  for (int i = 0; i < 16; i++) {
    int r = rb + i * 4;
    tile[r][cc] = f2bf(W[(size_t)(r0 + r) * ncols + c0 + cc]);
  }
  __syncthreads();
#pragma unroll
  for (int i = 0; i < 16; i++) {
    int n = rb + i * 4;
    WT[(size_t)(row_off + c0 + n) * 1024 + r0 + cc] = tile[cc][n];
  }
}

// ---------------- QKV GEMM (BM=128, BN=64) with fused QKNorm epilogue ----------------
// 4 waves; wave w owns rows w*32..w*32+31, all 64 cols (= one head).
__global__ void __launch_bounds__(256) gemm_qkv_kernel(const u16* __restrict__ A,
                                                       const u16* __restrict__ Bt,
                                                       const float* __restrict__ qw,
                                                       const float* __restrict__ kw,
                                                       u16* __restrict__ Qn,
                                                       u16* __restrict__ Kn,
                                                       u16* __restrict__ Vc) {
  __shared__ __align__(16) u16 ldsA[128 * 64];
  __shared__ __align__(16) u16 ldsB[64 * 64];
  const int K = 1024;
  int tid = threadIdx.x;
  int l = tid & 63, w = tid >> 6;
  int fr = l & 15, fg = l >> 4;
  int m0 = blockIdx.y * 128, n0 = blockIdx.x * 64;
  f32x4 acc[2][4];
#pragma unroll
  for (int i = 0; i < 2; i++)
#pragma unroll
    for (int j = 0; j < 4; j++) acc[i][j] = (f32x4)(0.0f);

  int lrow = l >> 3;
  int lcol = (l & 7) * 8;
  for (int k0 = 0; k0 < K; k0 += 64) {
#pragma unroll
    for (int i = 0; i < 4; i++) {
      int ci = w * 4 + i;  // 16 chunks x 8 rows = 128 rows
      gload16(A + (size_t)(m0 + ci * 8 + lrow) * K + k0 + lcol, ldsA + ci * 512);
    }
#pragma unroll
    for (int i = 0; i < 2; i++) {
      int ci = w * 2 + i;  // 8 chunks x 8 rows = 64 rows
      gload16(Bt + (size_t)(n0 + ci * 8 + lrow) * K + k0 + lcol, ldsB + ci * 512);
    }
    __syncthreads();
#pragma unroll
    for (int ks = 0; ks < 2; ks++) {
      short8 av[2], bv[4];
#pragma unroll
      for (int mb = 0; mb < 2; mb++)
        av[mb] = *(const short8*)(ldsA + (w * 32 + mb * 16 + fr) * 64 + ks * 32 + fg * 8);
#pragma unroll
      for (int nb = 0; nb < 4; nb++)
        bv[nb] = *(const short8*)(ldsB + (nb * 16 + fr) * 64 + ks * 32 + fg * 8);
#pragma unroll
      for (int mb = 0; mb < 2; mb++)
#pragma unroll
        for (int nb = 0; nb < 4; nb++)
          acc[mb][nb] = __builtin_amdgcn_mfma_f32_16x16x32_bf16(av[mb], bv[nb], acc[mb][nb], 0, 0, 0);
    }
    __syncthreads();
  }

  int m_base = m0 + w * 32;
  if (n0 < 1280) {
    const float* wptr = (n0 < 1024) ? qw : kw;
    float wv[4];
#pragma unroll
    for (int nb = 0; nb < 4; nb++) wv[nb] = wptr[nb * 16 + fr];
#pragma unroll
    for (int mb = 0; mb < 2; mb++)
#pragma unroll
      for (int r = 0; r < 4; r++) {
        float ss = acc[mb][0][r] * acc[mb][0][r] + acc[mb][1][r] * acc[mb][1][r] +
                   acc[mb][2][r] * acc[mb][2][r] + acc[mb][3][r] * acc[mb][3][r];
        ss += __shfl_xor(ss, 1, 64);
        ss += __shfl_xor(ss, 2, 64);
        ss += __shfl_xor(ss, 4, 64);
        ss += __shfl_xor(ss, 8, 64);
        float rn = rsqrtf(ss * (1.0f / 64.0f) + 1e-6f);
        int row = m_base + mb * 16 + fg * 4 + r;
        int b = row >> 11, t = row & 2047;
        size_t base;
        u16* dst;
        if (n0 < 1024) { dst = Qn; base = ((size_t)(b * 16 + (n0 >> 6)) * 2048 + t) * 64; }
        else           { dst = Kn; base = ((size_t)(b * 4 + ((n0 - 1024) >> 6)) * 2048 + t) * 64; }
#pragma unroll
        for (int nb = 0; nb < 4; nb++)
          dst[base + nb * 16 + fr] = f2bf(acc[mb][nb][r] * rn * wv[nb]);
      }
  } else {
    int kv = (n0 - 1280) >> 6;
#pragma unroll
    for (int mb = 0; mb < 2; mb++)
#pragma unroll
      for (int r = 0; r < 4; r++) {
        int row = m_base + mb * 16 + fg * 4 + r;
        int b = row >> 11, t = row & 2047;
        size_t base = ((size_t)(b * 4 + kv) * 2048 + t) * 64;
#pragma unroll
        for (int nb = 0; nb < 4; nb++)
          Vc[base + nb * 16 + fr] = f2bf(acc[mb][nb][r]);
      }
  }
}

// ---------------- out-proj GEMM (BM=128, BN=64): C fp32 = A bf16 @ Bt^T ----------------
__global__ void __launch_bounds__(256) gemm_bt_kernel(const u16* __restrict__ A,
                                                      const u16* __restrict__ Bt,
                                                      float* __restrict__ C,
                                                      int M, int N, int K) {
  __shared__ __align__(16) u16 ldsA[128 * 64];
  __shared__ __align__(16) u16 ldsB[64 * 64];
  int tid = threadIdx.x;
  int l = tid & 63, w = tid >> 6;
  int fr = l & 15, fg = l >> 4;
  int m0 = blockIdx.y * 128, n0 = blockIdx.x * 64;
  f32x4 acc[2][4];
#pragma unroll
  for (int i = 0; i < 2; i++)
#pragma unroll
    for (int j = 0; j < 4; j++) acc[i][j] = (f32x4)(0.0f);

  int lrow = l >> 3;
  int lcol = (l & 7) * 8;
  for (int k0 = 0; k0 < K; k0 += 64) {
#pragma unroll
    for (int i = 0; i < 4; i++) {
      int ci = w * 4 + i;
      gload16(A + (size_t)(m0 + ci * 8 + lrow) * K + k0 + lcol, ldsA + ci * 512);
    }
#pragma unroll
    for (int i = 0; i < 2; i++) {
      int ci = w * 2 + i;
      gload16(Bt + (size_t)(n0 + ci * 8 + lrow) * K + k0 + lcol, ldsB + ci * 512);
    }
    __syncthreads();
#pragma unroll
    for (int ks = 0; ks < 2; ks++) {
      short8 av[2], bv[4];
#pragma unroll
      for (int mb = 0; mb < 2; mb++)
        av[mb] = *(const short8*)(ldsA + (w * 32 + mb * 16 + fr) * 64 + ks * 32 + fg * 8);
#pragma unroll
      for (int nb = 0; nb < 4; nb++)
        bv[nb] = *(const short8*)(ldsB + (nb * 16 + fr) * 64 + ks * 32 + fg * 8);
#pragma unroll
      for (int mb = 0; mb < 2; mb++)
#pragma unroll
        for (int nb = 0; nb < 4; nb++)
          acc[mb][nb] = __builtin_amdgcn_mfma_f32_16x16x32_bf16(av[mb], bv[nb], acc[mb][nb], 0, 0, 0);
    }
    __syncthreads();
  }
#pragma unroll
  for (int mb = 0; mb < 2; mb++)
#pragma unroll
    for (int nb = 0; nb < 4; nb++)
#pragma unroll
      for (int r = 0; r < 4; r++)
        C[(size_t)(m0 + w * 32 + mb * 16 + fg * 4 + r) * N + (n0 + nb * 16 + fr)] =
            acc[mb][nb][r];
}

// ---------------- V transpose bf16 -> Vt[d][t] ----------------
__global__ void __launch_bounds__(256) vtrans_kernel(const u16* __restrict__ Vc,
                                                     u16* __restrict__ Vt) {
  __shared__ u16 tile[64][68];
  int bkv = blockIdx.y;
  int t0 = blockIdx.x * 64;
  int cc = threadIdx.x & 63, rb = threadIdx.x >> 6;
#pragma unroll
  for (int i = 0; i < 16; i++) {
    int tt = rb + i * 4;
    tile[tt][cc] = Vc[(size_t)(bkv * 2048 + t0 + tt) * 64 + cc];
  }
  __syncthreads();
#pragma unroll
  for (int i = 0; i < 16; i++) {
    int d = rb + i * 4;
    Vt[(size_t)(bkv * 64 + d) * 2048 + t0 + cc] = tile[cc][d];
  }
}

// ---------------- Flash attention (round-3 structure): 8 waves, QBLK=128 ----------------
// K+V cooperatively staged in LDS (dbuf) via global_load_lds with pre-swizzled source.
static __device__ __forceinline__ void stage_kv(const u16* Kb, const u16* Vb,
                                                u16* dstK, int kb0, int sr, int sc) {
  gload16(Kb + (size_t)(kb0 + sr) * 64 + sc, dstK);
  gload16(Vb + (size_t)sr * 2048 + kb0 + sc, dstK + 4096);
}

__global__ void __launch_bounds__(512) attn_kernel(const u16* __restrict__ Qn,
                                                   const u16* __restrict__ Kn,
                                                   const u16* __restrict__ Vt,
                                                   u16* __restrict__ AO) {
  __shared__ __align__(16) u16 ldsKV[2][8192];  // [buf][K:4096 | V:4096]
  __shared__ __align__(16) u16 plds[8][16][72];
  int tid = threadIdx.x;
  int w = tid >> 6, l = tid & 63;
  int fr = l & 15, fg = l >> 4;
  int i = blockIdx.x;
  int head = i & 31;
  // complement pairing: CU pair (i, i+256) sums to 34 tiles of work
  int qtile = (i < 256) ? (15 - (i >> 5)) : ((i >> 5) - 8);
  int b = head >> 4, h = head & 15;
  int kvh = h >> 2;
  const u16* Qb = Qn + (size_t)((b * 16 + h) * 2048) * 64;
  const u16* Kb = Kn + (size_t)((b * 4 + kvh) * 2048) * 64;
  const u16* Vb = Vt + (size_t)((b * 4 + kvh) * 64) * 2048;
  int qt0 = qtile * 128 + w * 16;

  short8 qf[2];
#pragma unroll
  for (int ks = 0; ks < 2; ks++)
    qf[ks] = *(const short8*)(Qb + (size_t)(qt0 + fr) * 64 + ks * 32 + fg * 8);

  f32x4 of[4];
#pragma unroll
  for (int ii = 0; ii < 4; ii++) of[ii] = (f32x4)(0.0f);
  float mrow = -1e30f, lsum = 0.0f;  // lane tracks q = qt0 + fr
  u16(*P)[72] = plds[w];

  int sr = tid >> 3;
  int sc = ((tid & 7) ^ (sr & 7)) * 8;
  int nt = 2 * qtile + 2;

  stage_kv(Kb, Vb, &ldsKV[0][w * 512], 0, sr, sc);

  for (int t = 0; t < nt; t++) {
    const u16* kbuf = ldsKV[t & 1];
    const u16* vbuf = kbuf + 4096;
    if (t + 1 < nt) {
      stage_kv(Kb, Vb, &ldsKV[(t + 1) & 1][w * 512], (t + 1) * 64, sr, sc);
      asm volatile("s_waitcnt vmcnt(2)" ::: "memory");
    } else {
      asm volatile("s_waitcnt vmcnt(0)" ::: "memory");
    }
    __builtin_amdgcn_s_barrier();
    asm volatile("" ::: "memory");

    int kb0 = t * 64;
    if (kb0 <= qt0 + 15) {
      // S^T = K Q^T : sf[kb][r] = S[k=kb0+kb*16+fg*4+r][q=qt0+fr]
      f32x4 sf[4];
#pragma unroll
      for (int kb = 0; kb < 4; kb++) sf[kb] = (f32x4)(0.0f);
      __builtin_amdgcn_s_setprio(1);
#pragma unroll
      for (int ks = 0; ks < 2; ks++) {
#pragma unroll
        for (int kb = 0; kb < 4; kb++) {
          short8 kf = *(const short8*)(kbuf + (kb * 16 + fr) * 64 +
                                       ((((ks << 2) + fg) ^ (fr & 7)) << 3));
          sf[kb] = __builtin_amdgcn_mfma_f32_16x16x32_bf16(kf, qf[ks], sf[kb], 0, 0, 0);
        }
      }
      __builtin_amdgcn_s_setprio(0);
      // soft cap in log2 domain
#pragma unroll
      for (int kb = 0; kb < 4; kb++)
#pragma unroll
        for (int r = 0; r < 4; r++) {
          float e = __builtin_amdgcn_exp2f(sf[kb][r] * CEXP2);
          sf[kb][r] = C1L - C2L * __builtin_amdgcn_rcpf(e + 1.0f);
        }
      if (kb0 + 63 > qt0) {  // diagonal: causal mask (k > q)
#pragma unroll
        for (int kb = 0; kb < 4; kb++)
#pragma unroll
          for (int r = 0; r < 4; r++)
            if (kb0 + kb * 16 + fg * 4 + r > qt0 + fr) sf[kb][r] = -1e30f;
      }
      // lane-local row stats + 2 shfl over fg bits
      float pmax = sf[0][0];
#pragma unroll
      for (int kb = 0; kb < 4; kb++)
#pragma unroll
        for (int r = 0; r < 4; r++) pmax = fmaxf(pmax, sf[kb][r]);
      pmax = fmaxf(pmax, __shfl_xor(pmax, 16, 64));
      pmax = fmaxf(pmax, __shfl_xor(pmax, 32, 64));
      float mnew = fmaxf(mrow, pmax);
      float alpha = __builtin_amdgcn_exp2f(mrow - mnew);
      mrow = mnew;
      float rs = 0.0f;
#pragma unroll
      for (int kb = 0; kb < 4; kb++)
#pragma unroll
        for (int r = 0; r < 4; r++) {
          float pf = __builtin_amdgcn_exp2f(sf[kb][r] - mnew);
          sf[kb][r] = pf;
          rs += pf;
        }
      rs += __shfl_xor(rs, 16, 64);
      rs += __shfl_xor(rs, 32, 64);
      lsum = lsum * alpha + rs;
#pragma unroll
      for (int r = 0; r < 4; r++) {
        float ar = __shfl(alpha, fg * 4 + r, 16);
#pragma unroll
        for (int db = 0; db < 4; db++) of[db][r] *= ar;
      }
      // pack P -> LDS (wave-private): P[q=fr][k=kb*16+fg*4+2rp]
#pragma unroll
      for (int kb = 0; kb < 4; kb++)
#pragma unroll
        for (int rp = 0; rp < 2; rp++) {
          unsigned pk;
          asm("v_cvt_pk_bf16_f32 %0, %1, %2" : "=v"(pk)
              : "v"(sf[kb][2 * rp]), "v"(sf[kb][2 * rp + 1]));
          *(unsigned*)(&P[fr][kb * 16 + fg * 4 + 2 * rp]) = pk;
        }
      short8 pa[2];
#pragma unroll
      for (int ks = 0; ks < 2; ks++)
        pa[ks] = *(const short8*)(&P[fr][ks * 32 + fg * 8]);
      __builtin_amdgcn_s_setprio(1);
#pragma unroll
      for (int ks = 0; ks < 2; ks++)
#pragma unroll
        for (int db = 0; db < 4; db++) {
          short8 vf = *(const short8*)(vbuf + (db * 16 + fr) * 64 +
                                       ((((ks << 2) + fg) ^ (fr & 7)) << 3));
          of[db] = __builtin_amdgcn_mfma_f32_16x16x32_bf16(pa[ks], vf, of[db], 0, 0, 0);
        }
      __builtin_amdgcn_s_setprio(0);
    }
    asm volatile("" ::: "memory");
    __builtin_amdgcn_s_barrier();
  }
  float linv = __builtin_amdgcn_rcpf(lsum);
#pragma unroll
  for (int r = 0; r < 4; r++) {
    float li = __shfl(linv, fg * 4 + r, 16);
#pragma unroll
    for (int db = 0; db < 4; db++)
      AO[(size_t)(b * 2048 + qt0 + fg * 4 + r) * 1024 + h * 64 + db * 16 + fr] =
          f2bf(of[db][r] * li);
  }
}

extern "C" void kernel_launch(void* const* d_in, const int* in_sizes, int n_in,
                              void* d_out, int out_size, void* d_ws, size_t ws_size,
                              hipStream_t stream) {
  (void)in_sizes; (void)n_in; (void)out_size; (void)ws_size;
  const float* x  = (const float*)d_in[0];
  const float* Wq = (const float*)d_in[1];
  const float* Wk = (const float*)d_in[2];
  const float* Wv = (const float*)d_in[3];
  const float* Wo = (const float*)d_in[4];
  const float* qw = (const float*)d_in[5];
  const float* kw = (const float*)d_in[6];
  float* out = (float*)d_out;

  char* p = (char*)d_ws;
  u16* xb    = (u16*)p;   p += (size_t)4096 * 1024 * 2;
  u16* WqkvT = (u16*)p;   p += (size_t)1536 * 1024 * 2;
  u16* WoT   = (u16*)p;   p += (size_t)1024 * 1024 * 2;
  u16* Qn    = (u16*)p;   p += (size_t)2 * 16 * 2048 * 64 * 2;
  u16* Kn    = (u16*)p;   p += (size_t)2 * 4 * 2048 * 64 * 2;
  u16* Vc    = (u16*)p;   p += (size_t)2 * 4 * 2048 * 64 * 2;
  u16* Vt    = (u16*)p;   p += (size_t)2 * 4 * 64 * 2048 * 2;
  u16* AO    = (u16*)p;   p += (size_t)4096 * 1024 * 2;

  cast_x_kernel<<<2048, 256, 0, stream>>>(x, xb, 4096 * 1024);
  wtrans_all_kernel<<<640, 256, 0, stream>>>(Wq, Wk, Wv, Wo, WqkvT, WoT);
  gemm_qkv_kernel<<<dim3(24, 32), 256, 0, stream>>>(xb, WqkvT, qw, kw, Qn, Kn, Vc);
  vtrans_kernel<<<dim3(32, 8), 256, 0, stream>>>(Vc, Vt);
  attn_kernel<<<512, 512, 0, stream>>>(Qn, Kn, Vt, AO);
  gemm_bt_kernel<<<dim3(16, 32), 256, 0, stream>>>(AO, WoT, out, 4096, 1024, 1024);
}

// Round 8
// 174.628 us; speedup vs baseline: 1.3927x; 1.1023x over previous
//
#include <hip/hip_runtime.h>
#include <stdint.h>

typedef unsigned short u16;
typedef __attribute__((ext_vector_type(8))) short short8;
typedef __attribute__((ext_vector_type(4))) float f32x4;
typedef __attribute__((ext_vector_type(8))) u16 u16x8;

// soft-cap in log2 domain via odd quintic: 50*log2e*tanh(s/400) = s*(A1 + A3 s^2 + A5 s^4)
// valid because QKNorm bounds |s| <= 64 (|x|<=0.16; poly error < 1e-6)
#define A1T 0.18033688f
#define A3T -3.7570183e-7f
#define A5T 9.3925e-13f
#define MST 11.5f   // static max: max |pl| = 11.445

static __device__ __forceinline__ u16 f2bf(float f) {
  union { float f; unsigned u; } v; v.f = f;
  unsigned r = v.u + 0x7fffu + ((v.u >> 16) & 1u);
  return (u16)(r >> 16);
}

static __device__ __forceinline__ void gload16(const void* g, void* l) {
  __builtin_amdgcn_global_load_lds(
      (const __attribute__((address_space(1))) void*)g,
      (__attribute__((address_space(3))) void*)l, 16, 0, 0);
}

// ---------------- cast x fp32 -> bf16 ----------------
__global__ void __launch_bounds__(256) cast_x_kernel(const float* __restrict__ x,
                                                     u16* __restrict__ xb, int n) {
  int i = (blockIdx.x * 256 + threadIdx.x) * 8;
  if (i >= n) return;
  f32x4 a = *(const f32x4*)(x + i);
  f32x4 b = *(const f32x4*)(x + i + 4);
  u16x8 o;
  o[0] = f2bf(a[0]); o[1] = f2bf(a[1]); o[2] = f2bf(a[2]); o[3] = f2bf(a[3]);
  o[4] = f2bf(b[0]); o[5] = f2bf(b[1]); o[6] = f2bf(b[2]); o[7] = f2bf(b[3]);
  *(u16x8*)(xb + i) = o;
}

// ------- all 4 weight transposes in one launch -------
__global__ void __launch_bounds__(256) wtrans_all_kernel(const float* __restrict__ Wq,
                                                         const float* __restrict__ Wk,
                                                         const float* __restrict__ Wv,
                                                         const float* __restrict__ Wo,
                                                         u16* __restrict__ WqkvT,
                                                         u16* __restrict__ WoT) {
  __shared__ u16 tile[64][68];
  int id = blockIdx.x;
  const float* W; u16* WT; int ncols, row_off, cx, ry;
  if (id < 256)      { W = Wq; WT = WqkvT; ncols = 1024; row_off = 0;    cx = id & 15;        ry = id >> 4; }
  else if (id < 320) { W = Wk; WT = WqkvT; ncols = 256;  row_off = 1024; cx = (id - 256) & 3; ry = (id - 256) >> 2; }
  else if (id < 384) { W = Wv; WT = WqkvT; ncols = 256;  row_off = 1280; cx = (id - 320) & 3; ry = (id - 320) >> 2; }
  else               { W = Wo; WT = WoT;   ncols = 1024; row_off = 0;    cx = (id - 384) & 15; ry = (id - 384) >> 4; }
  int c0 = cx * 64, r0 = ry * 64;
  int cc = threadIdx.x & 63, rb = threadIdx.x >> 6;
#pragma unroll
  for (int i = 0; i < 16; i++) {
    int r = rb + i * 4;
    tile[r][cc] = f2bf(W[(size_t)(r0 + r) * ncols + c0 + cc]);
  }
  __syncthreads();
#pragma unroll
  for (int i = 0; i < 16; i++) {
    int n = rb + i * 4;
    WT[(size_t)(row_off + c0 + n) * 1024 + r0 + cc] = tile[cc][n];
  }
}

// ---------------- QKV GEMM (BM=128, BN=64) with fused QKNorm epilogue ----------------
__global__ void __launch_bounds__(256) gemm_qkv_kernel(const u16* __restrict__ A,
                                                       const u16* __restrict__ Bt,
                                                       const float* __restrict__ qw,
                                                       const float* __restrict__ kw,
                                                       u16* __restrict__ Qn,
                                                       u16* __restrict__ Kn,
                                                       u16* __restrict__ Vc) {
  __shared__ __align__(16) u16 ldsA[128 * 64];
  __shared__ __align__(16) u16 ldsB[64 * 64];
  const int K = 1024;
  int tid = threadIdx.x;
  int l = tid & 63, w = tid >> 6;
  int fr = l & 15, fg = l >> 4;
  int m0 = blockIdx.y * 128, n0 = blockIdx.x * 64;
  f32x4 acc[2][4];
#pragma unroll
  for (int i = 0; i < 2; i++)
#pragma unroll
    for (int j = 0; j < 4; j++) acc[i][j] = (f32x4)(0.0f);

  int lrow = l >> 3;
  int lcol = (l & 7) * 8;
  for (int k0 = 0; k0 < K; k0 += 64) {
#pragma unroll
    for (int i = 0; i < 4; i++) {
      int ci = w * 4 + i;
      gload16(A + (size_t)(m0 + ci * 8 + lrow) * K + k0 + lcol, ldsA + ci * 512);
    }
#pragma unroll
    for (int i = 0; i < 2; i++) {
      int ci = w * 2 + i;
      gload16(Bt + (size_t)(n0 + ci * 8 + lrow) * K + k0 + lcol, ldsB + ci * 512);
    }
    __syncthreads();
#pragma unroll
    for (int ks = 0; ks < 2; ks++) {
      short8 av[2], bv[4];
#pragma unroll
      for (int mb = 0; mb < 2; mb++)
        av[mb] = *(const short8*)(ldsA + (w * 32 + mb * 16 + fr) * 64 + ks * 32 + fg * 8);
#pragma unroll
      for (int nb = 0; nb < 4; nb++)
        bv[nb] = *(const short8*)(ldsB + (nb * 16 + fr) * 64 + ks * 32 + fg * 8);
#pragma unroll
      for (int mb = 0; mb < 2; mb++)
#pragma unroll
        for (int nb = 0; nb < 4; nb++)
          acc[mb][nb] = __builtin_amdgcn_mfma_f32_16x16x32_bf16(av[mb], bv[nb], acc[mb][nb], 0, 0, 0);
    }
    __syncthreads();
  }

  int m_base = m0 + w * 32;
  if (n0 < 1280) {
    const float* wptr = (n0 < 1024) ? qw : kw;
    float wv[4];
#pragma unroll
    for (int nb = 0; nb < 4; nb++) wv[nb] = wptr[nb * 16 + fr];
#pragma unroll
    for (int mb = 0; mb < 2; mb++)
#pragma unroll
      for (int r = 0; r < 4; r++) {
        float ss = acc[mb][0][r] * acc[mb][0][r] + acc[mb][1][r] * acc[mb][1][r] +
                   acc[mb][2][r] * acc[mb][2][r] + acc[mb][3][r] * acc[mb][3][r];
        ss += __shfl_xor(ss, 1, 64);
        ss += __shfl_xor(ss, 2, 64);
        ss += __shfl_xor(ss, 4, 64);
        ss += __shfl_xor(ss, 8, 64);
        float rn = rsqrtf(ss * (1.0f / 64.0f) + 1e-6f);
        int row = m_base + mb * 16 + fg * 4 + r;
        int b = row >> 11, t = row & 2047;
        size_t base;
        u16* dst;
        if (n0 < 1024) { dst = Qn; base = ((size_t)(b * 16 + (n0 >> 6)) * 2048 + t) * 64; }
        else           { dst = Kn; base = ((size_t)(b * 4 + ((n0 - 1024) >> 6)) * 2048 + t) * 64; }
#pragma unroll
        for (int nb = 0; nb < 4; nb++)
          dst[base + nb * 16 + fr] = f2bf(acc[mb][nb][r] * rn * wv[nb]);
      }
  } else {
    int kv = (n0 - 1280) >> 6;
#pragma unroll
    for (int mb = 0; mb < 2; mb++)
#pragma unroll
      for (int r = 0; r < 4; r++) {
        int row = m_base + mb * 16 + fg * 4 + r;
        int b = row >> 11, t = row & 2047;
        size_t base = ((size_t)(b * 4 + kv) * 2048 + t) * 64;
#pragma unroll
        for (int nb = 0; nb < 4; nb++)
          Vc[base + nb * 16 + fr] = f2bf(acc[mb][nb][r]);
      }
  }
}

// ---------------- out-proj GEMM (BM=128, BN=64) ----------------
__global__ void __launch_bounds__(256) gemm_bt_kernel(const u16* __restrict__ A,
                                                      const u16* __restrict__ Bt,
                                                      float* __restrict__ C,
                                                      int M, int N, int K) {
  __shared__ __align__(16) u16 ldsA[128 * 64];
  __shared__ __align__(16) u16 ldsB[64 * 64];
  int tid = threadIdx.x;
  int l = tid & 63, w = tid >> 6;
  int fr = l & 15, fg = l >> 4;
  int m0 = blockIdx.y * 128, n0 = blockIdx.x * 64;
  f32x4 acc[2][4];
#pragma unroll
  for (int i = 0; i < 2; i++)
#pragma unroll
    for (int j = 0; j < 4; j++) acc[i][j] = (f32x4)(0.0f);

  int lrow = l >> 3;
  int lcol = (l & 7) * 8;
  for (int k0 = 0; k0 < K; k0 += 64) {
#pragma unroll
    for (int i = 0; i < 4; i++) {
      int ci = w * 4 + i;
      gload16(A + (size_t)(m0 + ci * 8 + lrow) * K + k0 + lcol, ldsA + ci * 512);
    }
#pragma unroll
    for (int i = 0; i < 2; i++) {
      int ci = w * 2 + i;
      gload16(Bt + (size_t)(n0 + ci * 8 + lrow) * K + k0 + lcol, ldsB + ci * 512);
    }
    __syncthreads();
#pragma unroll
    for (int ks = 0; ks < 2; ks++) {
      short8 av[2], bv[4];
#pragma unroll
      for (int mb = 0; mb < 2; mb++)
        av[mb] = *(const short8*)(ldsA + (w * 32 + mb * 16 + fr) * 64 + ks * 32 + fg * 8);
#pragma unroll
      for (int nb = 0; nb < 4; nb++)
        bv[nb] = *(const short8*)(ldsB + (nb * 16 + fr) * 64 + ks * 32 + fg * 8);
#pragma unroll
      for (int mb = 0; mb < 2; mb++)
#pragma unroll
        for (int nb = 0; nb < 4; nb++)
          acc[mb][nb] = __builtin_amdgcn_mfma_f32_16x16x32_bf16(av[mb], bv[nb], acc[mb][nb], 0, 0, 0);
    }
    __syncthreads();
  }
#pragma unroll
  for (int mb = 0; mb < 2; mb++)
#pragma unroll
    for (int nb = 0; nb < 4; nb++)
#pragma unroll
      for (int r = 0; r < 4; r++)
        C[(size_t)(m0 + w * 32 + mb * 16 + fg * 4 + r) * N + (n0 + nb * 16 + fr)] =
            acc[mb][nb][r];
}

// ---------------- V transpose bf16 -> Vt[d][t] ----------------
__global__ void __launch_bounds__(256) vtrans_kernel(const u16* __restrict__ Vc,
                                                     u16* __restrict__ Vt) {
  __shared__ u16 tile[64][68];
  int bkv = blockIdx.y;
  int t0 = blockIdx.x * 64;
  int cc = threadIdx.x & 63, rb = threadIdx.x >> 6;
#pragma unroll
  for (int i = 0; i < 16; i++) {
    int tt = rb + i * 4;
    tile[tt][cc] = Vc[(size_t)(bkv * 2048 + t0 + tt) * 64 + cc];
  }
  __syncthreads();
#pragma unroll
  for (int i = 0; i < 16; i++) {
    int d = rb + i * 4;
    Vt[(size_t)(bkv * 64 + d) * 2048 + t0 + cc] = tile[cc][d];
  }
}

// ---------------- Flash attention: 8 waves, QBLK=128, poly soft-cap + static max ----------------
static __device__ __forceinline__ void stage_kv(const u16* Kb, const u16* Vb,
                                                u16* dstK, int kb0, int sr, int sc) {
  gload16(Kb + (size_t)(kb0 + sr) * 64 + sc, dstK);
  gload16(Vb + (size_t)sr * 2048 + kb0 + sc, dstK + 4096);
}

__global__ void __launch_bounds__(512) attn_kernel(const u16* __restrict__ Qn,
                                                   const u16* __restrict__ Kn,
                                                   const u16* __restrict__ Vt,
                                                   u16* __restrict__ AO) {
  __shared__ __align__(16) u16 ldsKV[2][8192];  // [buf][K:4096 | V:4096]
  __shared__ __align__(16) u16 plds[8][16][72];
  int tid = threadIdx.x;
  int w = tid >> 6, l = tid & 63;
  int fr = l & 15, fg = l >> 4;
  int i = blockIdx.x;
  int head = i & 31;
  // complement pairing: CU pair (i, i+256) sums to 34 tiles of work
  int qtile = (i < 256) ? (15 - (i >> 5)) : ((i >> 5) - 8);
  int b = head >> 4, h = head & 15;
  int kvh = h >> 2;
  const u16* Qb = Qn + (size_t)((b * 16 + h) * 2048) * 64;
  const u16* Kb = Kn + (size_t)((b * 4 + kvh) * 2048) * 64;
  const u16* Vb = Vt + (size_t)((b * 4 + kvh) * 64) * 2048;
  int qt0 = qtile * 128 + w * 16;

  short8 qf[2];
#pragma unroll
  for (int ks = 0; ks < 2; ks++)
    qf[ks] = *(const short8*)(Qb + (size_t)(qt0 + fr) * 64 + ks * 32 + fg * 8);

  f32x4 of[4];
#pragma unroll
  for (int ii = 0; ii < 4; ii++) of[ii] = (f32x4)(0.0f);
  float lsum = 0.0f;  // lane-local partial; q = qt0 + fr
  u16(*P)[72] = plds[w];

  int sr = tid >> 3;
  int sc = ((tid & 7) ^ (sr & 7)) * 8;
  int nt = 2 * qtile + 2;

  stage_kv(Kb, Vb, &ldsKV[0][w * 512], 0, sr, sc);

  for (int t = 0; t < nt; t++) {
    const u16* kbuf = ldsKV[t & 1];
    const u16* vbuf = kbuf + 4096;
    if (t + 1 < nt) {
      stage_kv(Kb, Vb, &ldsKV[(t + 1) & 1][w * 512], (t + 1) * 64, sr, sc);
      asm volatile("s_waitcnt vmcnt(2)" ::: "memory");
    } else {
      asm volatile("s_waitcnt vmcnt(0)" ::: "memory");
    }
    __builtin_amdgcn_s_barrier();
    asm volatile("" ::: "memory");

    int kb0 = t * 64;
    if (kb0 <= qt0 + 15) {
      // S^T = K Q^T : sf[kb][r] = S[k=kb0+kb*16+fg*4+r][q=qt0+fr]
      f32x4 sf[4];
#pragma unroll
      for (int kb = 0; kb < 4; kb++) sf[kb] = (f32x4)(0.0f);
      __builtin_amdgcn_s_setprio(1);
#pragma unroll
      for (int ks = 0; ks < 2; ks++) {
#pragma unroll
        for (int kb = 0; kb < 4; kb++) {
          short8 kf = *(const short8*)(kbuf + (kb * 16 + fr) * 64 +
                                       ((((ks << 2) + fg) ^ (fr & 7)) << 3));
          sf[kb] = __builtin_amdgcn_mfma_f32_16x16x32_bf16(kf, qf[ks], sf[kb], 0, 0, 0);
        }
      }
      __builtin_amdgcn_s_setprio(0);
      // p = exp2(pl - M), pl = s*(A1 + A3 s^2 + A5 s^4); no running max needed
      float rs = 0.0f;
#pragma unroll
      for (int kb = 0; kb < 4; kb++)
#pragma unroll
        for (int r = 0; r < 4; r++) {
          float s = sf[kb][r];
          float s2 = s * s;
          float pq = fmaf(s2, A5T, A3T);
          float pc = fmaf(s2, pq, A1T);
          sf[kb][r] = __builtin_amdgcn_exp2f(fmaf(s, pc, -MST));
        }
      if (kb0 + 63 > qt0) {  // diagonal: causal mask (k > q)
#pragma unroll
        for (int kb = 0; kb < 4; kb++)
#pragma unroll
          for (int r = 0; r < 4; r++)
            if (kb0 + kb * 16 + fg * 4 + r > qt0 + fr) sf[kb][r] = 0.0f;
      }
#pragma unroll
      for (int kb = 0; kb < 4; kb++)
#pragma unroll
        for (int r = 0; r < 4; r++) rs += sf[kb][r];
      lsum += rs;
      // pack P -> LDS (wave-private): P[q=fr][k=kb*16+fg*4+2rp]
#pragma unroll
      for (int kb = 0; kb < 4; kb++)
#pragma unroll
        for (int rp = 0; rp < 2; rp++) {
          unsigned pk;
          asm("v_cvt_pk_bf16_f32 %0, %1, %2" : "=v"(pk)
              : "v"(sf[kb][2 * rp]), "v"(sf[kb][2 * rp + 1]));
          *(unsigned*)(&P[fr][kb * 16 + fg * 4 + 2 * rp]) = pk;
        }
      short8 pa[2];
#pragma unroll
      for (int ks = 0; ks < 2; ks++)
        pa[ks] = *(const short8*)(&P[fr][ks * 32 + fg * 8]);
      __builtin_amdgcn_s_setprio(1);
#pragma unroll
      for (int ks = 0; ks < 2; ks++)
#pragma unroll
        for (int db = 0; db < 4; db++) {
          short8 vf = *(const short8*)(vbuf + (db * 16 + fr) * 64 +
                                       ((((ks << 2) + fg) ^ (fr & 7)) << 3));
          of[db] = __builtin_amdgcn_mfma_f32_16x16x32_bf16(pa[ks], vf, of[db], 0, 0, 0);
        }
      __builtin_amdgcn_s_setprio(0);
    }
    asm volatile("" ::: "memory");
    __builtin_amdgcn_s_barrier();
  }
  // single final reduce across fg groups (lanes fr, fr+16, fr+32, fr+48 share q)
  lsum += __shfl_xor(lsum, 16, 64);
  lsum += __shfl_xor(lsum, 32, 64);
  float linv = __builtin_amdgcn_rcpf(lsum);
#pragma unroll
  for (int r = 0; r < 4; r++) {
    float li = __shfl(linv, fg * 4 + r, 16);
#pragma unroll
    for (int db = 0; db < 4; db++)
      AO[(size_t)(b * 2048 + qt0 + fg * 4 + r) * 1024 + h * 64 + db * 16 + fr] =
          f2bf(of[db][r] * li);
  }
}

extern "C" void kernel_launch(void* const* d_in, const int* in_sizes, int n_in,
                              void* d_out, int out_size, void* d_ws, size_t ws_size,
                              hipStream_t stream) {
  (void)in_sizes; (void)n_in; (void)out_size; (void)ws_size;
  const float* x  = (const float*)d_in[0];
  const float* Wq = (const float*)d_in[1];
  const float* Wk = (const float*)d_in[2];
  const float* Wv = (const float*)d_in[3];
  const float* Wo = (const float*)d_in[4];
  const float* qw = (const float*)d_in[5];
  const float* kw = (const float*)d_in[6];
  float* out = (float*)d_out;

  char* p = (char*)d_ws;
  u16* xb    = (u16*)p;   p += (size_t)4096 * 1024 * 2;
  u16* WqkvT = (u16*)p;   p += (size_t)1536 * 1024 * 2;
  u16* WoT   = (u16*)p;   p += (size_t)1024 * 1024 * 2;
  u16* Qn    = (u16*)p;   p += (size_t)2 * 16 * 2048 * 64 * 2;
  u16* Kn    = (u16*)p;   p += (size_t)2 * 4 * 2048 * 64 * 2;
  u16* Vc    = (u16*)p;   p += (size_t)2 * 4 * 2048 * 64 * 2;
  u16* Vt    = (u16*)p;   p += (size_t)2 * 4 * 64 * 2048 * 2;
  u16* AO    = (u16*)p;   p += (size_t)4096 * 1024 * 2;

  cast_x_kernel<<<2048, 256, 0, stream>>>(x, xb, 4096 * 1024);
  wtrans_all_kernel<<<640, 256, 0, stream>>>(Wq, Wk, Wv, Wo, WqkvT, WoT);
  gemm_qkv_kernel<<<dim3(24, 32), 256, 0, stream>>>(xb, WqkvT, qw, kw, Qn, Kn, Vc);
  vtrans_kernel<<<dim3(32, 8), 256, 0, stream>>>(Vc, Vt);
  attn_kernel<<<512, 512, 0, stream>>>(Qn, Kn, Vt, AO);
  gemm_bt_kernel<<<dim3(16, 32), 256, 0, stream>>>(AO, WoT, out, 4096, 1024, 1024);
}